// Round 1
// baseline (1168.625 us; speedup 1.0000x reference)
//
#include <hip/hip_runtime.h>
#include <hip/hip_bf16.h>
#include <stdint.h>

// Problem constants (MixtralAttention: B=2, S=2048, H=4096, 32 q-heads, 8 kv-heads, HD=128)
#define Hdim 4096
#define NH 32
#define NKV 8
#define HDs 128
#define Bb 2
#define Ss 2048
#define QKV_N 6144              // NH*HD + 2*NKV*HD
#define SCALEF 0.08838834764831845f   // 128^-0.5
// sliding window = 4096 >= S=2048  ->  pure causal mask

typedef __attribute__((ext_vector_type(4))) float f32x4;
typedef __attribute__((ext_vector_type(8))) short bf16x8;

__device__ __forceinline__ unsigned short f2bf(float f) {
  union { float f; unsigned u; } v; v.f = f;
  unsigned r = v.u + 0x7fffu + ((v.u >> 16) & 1u);   // RNE
  return (unsigned short)(r >> 16);
}
__device__ __forceinline__ float bf2f(unsigned short h) {
  union { unsigned u; float f; } v; v.u = ((unsigned)h) << 16;
  return v.f;
}

#define GLOBAL_AS(p) ((const __attribute__((address_space(1))) void*)(p))
#define LDS_AS(p)    ((__attribute__((address_space(3))) void*)(p))

// ---------------- fp32 -> bf16 elementwise (hidden_states) ----------------
__global__ void k_f32_to_bf16(const float* __restrict__ src, unsigned short* __restrict__ dst, int n) {
  int i = (blockIdx.x * blockDim.x + threadIdx.x) * 4;
  if (i >= n) return;
  f32x4 v = *(const f32x4*)(src + i);
  uint2 o;
  o.x = (unsigned)f2bf(v.x) | ((unsigned)f2bf(v.y) << 16);
  o.y = (unsigned)f2bf(v.z) | ((unsigned)f2bf(v.w) << 16);
  *(uint2*)(dst + i) = o;
}

// ---------------- fp32 [K][N] -> bf16 [N][K] tile transpose (weights) ----------------
__global__ void k_transpose_bf16(const float* __restrict__ src, unsigned short* __restrict__ dst,
                                 int K, int N) {
  __shared__ unsigned short tile[32][33];
  int n0 = blockIdx.x * 32, k0 = blockIdx.y * 32;
  int tx = threadIdx.x, ty0 = threadIdx.y;
#pragma unroll
  for (int i = 0; i < 4; i++) {
    int ty = ty0 + i * 8;
    tile[ty][tx] = f2bf(src[(size_t)(k0 + ty) * N + n0 + tx]);
  }
  __syncthreads();
#pragma unroll
  for (int i = 0; i < 4; i++) {
    int ty = ty0 + i * 8;
    dst[(size_t)(n0 + ty) * K + k0 + tx] = tile[tx][ty];
  }
}

// ---------------- bf16 GEMM: C[M][N] = A[M][K] * Bt[N][K]^T  (m97-style 128x128, BK=32) ----------
template <int OUT_BF16>
__global__ __launch_bounds__(256) void k_gemm(const unsigned short* __restrict__ A,
                                              const unsigned short* __restrict__ Bt,
                                              void* __restrict__ C,
                                              int M, int N, int K, int nbn) {
  __shared__ __align__(16) unsigned short As[128 * 32];
  __shared__ __align__(16) unsigned short Bs[128 * 32];
  int bn = blockIdx.x % nbn, bm = blockIdx.x / nbn;
  int t = threadIdx.x;
  int lane = t & 63, w = t >> 6;
  int wm = w >> 1, wn = w & 1;
  int l15 = lane & 15, l4 = lane >> 4;

  f32x4 zero = {0.f, 0.f, 0.f, 0.f};
  f32x4 acc[4][4];
#pragma unroll
  for (int m = 0; m < 4; m++)
#pragma unroll
    for (int n = 0; n < 4; n++) acc[m][n] = zero;

  size_t arow0 = (size_t)bm * 128 * K;
  size_t brow0 = (size_t)bn * 128 * K;
  int srow = t >> 2;            // 0..63
  int sko = (t & 3) * 8;        // 0,8,16,24

  for (int ks = 0; ks < K; ks += 32) {
#pragma unroll
    for (int c = 0; c < 2; c++) {
      int row = c * 64 + srow;
      const unsigned short* ga = A + arow0 + (size_t)row * K + ks + sko;
      const unsigned short* gb = Bt + brow0 + (size_t)row * K + ks + sko;
      __builtin_amdgcn_global_load_lds(GLOBAL_AS(ga), LDS_AS(As + c * 2048 + w * 512), 16, 0, 0);
      __builtin_amdgcn_global_load_lds(GLOBAL_AS(gb), LDS_AS(Bs + c * 2048 + w * 512), 16, 0, 0);
    }
    __syncthreads();
    bf16x8 af[4], bfr[4];
#pragma unroll
    for (int m = 0; m < 4; m++)
      af[m] = *(const bf16x8*)&As[(wm * 64 + m * 16 + l15) * 32 + l4 * 8];
#pragma unroll
    for (int n = 0; n < 4; n++)
      bfr[n] = *(const bf16x8*)&Bs[(wn * 64 + n * 16 + l15) * 32 + l4 * 8];
#pragma unroll
    for (int m = 0; m < 4; m++)
#pragma unroll
      for (int n = 0; n < 4; n++)
        acc[m][n] = __builtin_amdgcn_mfma_f32_16x16x32_bf16(af[m], bfr[n], acc[m][n], 0, 0, 0);
    __syncthreads();
  }
  // C/D layout: col = lane&15, row = (lane>>4)*4 + reg   [verified m89/m91]
#pragma unroll
  for (int m = 0; m < 4; m++)
#pragma unroll
    for (int n = 0; n < 4; n++) {
      int col = bn * 128 + wn * 64 + n * 16 + l15;
#pragma unroll
      for (int r = 0; r < 4; r++) {
        int row = bm * 128 + wm * 64 + m * 16 + l4 * 4 + r;
        float v = acc[m][n][r];
        if (OUT_BF16)
          ((unsigned short*)C)[(size_t)row * N + col] = f2bf(v);
        else
          ((float*)C)[(size_t)row * N + col] = v;
      }
    }
}

// ---------------- RoPE (interleaved pairs) in-place on bf16 qkv; folds SCALE into q ------------
__global__ void k_rope(unsigned short* __restrict__ qkv, const int* __restrict__ pos) {
  int bs = blockIdx.y;                       // b*S + s
  int t = threadIdx.x;                       // 256
  int head = blockIdx.x * 4 + (t >> 6);      // 0..39 (0-31 q, 32-39 k)
  int p = t & 63;                            // pair index
  int col;
  float scale;
  if (head < NH) { col = head * HDs + 2 * p; scale = SCALEF; }
  else           { col = NH * HDs + (head - NH) * HDs + 2 * p; scale = 1.f; }
  size_t idx = (size_t)bs * QKV_N + col;
  float x0 = bf2f(qkv[idx]), x1 = bf2f(qkv[idx + 1]);
  float position = (float)pos[bs];
  // inv_freq = 10000^(-2p/128) = exp2(-p * 2*log2(10000)/128)
  float inv_freq = exp2f((float)p * -0.2076205059304601f);
  float ang = position * inv_freq;
  float sv, cv;
  sincosf(ang, &sv, &cv);
  float o0 = (x0 * cv - x1 * sv) * scale;
  float o1 = (x1 * cv + x0 * sv) * scale;
  qkv[idx]     = f2bf(o0);
  qkv[idx + 1] = f2bf(o1);
}

// ---------------- V repack: qkv v-part [s][d] -> vt[b][kv][d][s] (bf16 tile transpose) ---------
__global__ void k_vt(const unsigned short* __restrict__ qkv, unsigned short* __restrict__ vt) {
  __shared__ unsigned short tile[32][33];
  int bkv = blockIdx.z;                 // b*NKV + kvh
  int d0 = blockIdx.y * 32;
  int s0 = blockIdx.x * 32;
  int b = bkv >> 3, kvh = bkv & 7;
  int tx = threadIdx.x, ty0 = threadIdx.y;
  const unsigned short* src = qkv + (size_t)b * Ss * QKV_N + NH * HDs + NKV * HDs + kvh * HDs;
#pragma unroll
  for (int i = 0; i < 4; i++) {
    int ty = ty0 + i * 8;
    tile[ty][tx] = src[(size_t)(s0 + ty) * QKV_N + d0 + tx];
  }
  __syncthreads();
  unsigned short* dst = vt + (size_t)bkv * HDs * Ss;
#pragma unroll
  for (int i = 0; i < 4; i++) {
    int ty = ty0 + i * 8;
    dst[(size_t)(d0 + ty) * Ss + s0 + tx] = tile[tx][ty];
  }
}

// ---------------- Flash attention: 1 wave per (b, head, 16-row q tile), causal --------------
// Swapped QK^T: S^T = mfma(A=K, B=Q^T) so softmax reduce is shfl over lane-groups.
__global__ __launch_bounds__(64) void k_attn(const unsigned short* __restrict__ qkv,
                                             const unsigned short* __restrict__ vt,
                                             unsigned short* __restrict__ out) {
  __shared__ __align__(16) unsigned short p_lds[16 * 32];
  int x = blockIdx.x;
  int qt = x & 127;            // S/16 = 128 q tiles
  int h = (x >> 7) & 31;
  int b = x >> 12;
  int kvh = h >> 2;            // GROUP = 4
  int lane = threadIdx.x;
  int l15 = lane & 15, l4 = lane >> 4;
  int qb = qt * 16;

  // Q fragments (B-operand): Q[qb+l15][ch*32 + l4*8 + e]; SCALE already folded in by rope
  const size_t qrow = ((size_t)(b * Ss) + qb + l15) * QKV_N + (size_t)h * HDs;
  bf16x8 qf[4];
#pragma unroll
  for (int ch = 0; ch < 4; ch++)
    qf[ch] = *(const bf16x8*)&qkv[qrow + ch * 32 + l4 * 8];

  f32x4 zero = {0.f, 0.f, 0.f, 0.f};
  f32x4 acc[8];
#pragma unroll
  for (int dt = 0; dt < 8; dt++) acc[dt] = zero;
  float mrun = -1e30f, lsum = 0.f;   // stats for q = l&15

  const unsigned short* kbase = qkv + (size_t)b * Ss * QKV_N + NH * HDs + (size_t)kvh * HDs;
  const unsigned short* vbase = vt + ((size_t)(b * NKV + kvh)) * HDs * Ss;
  int ntiles = (qb + 16 + 31) >> 5;   // 32-wide kv tiles covering kv <= qb+15 (stays in-bounds)

  for (int kt = 0; kt < ntiles; kt++) {
    int kvb = kt * 32;
    f32x4 s0 = zero, s1 = zero;
#pragma unroll
    for (int ch = 0; ch < 4; ch++) {
      bf16x8 k0 = *(const bf16x8*)&kbase[(size_t)(kvb + l15) * QKV_N + ch * 32 + l4 * 8];
      bf16x8 k1 = *(const bf16x8*)&kbase[(size_t)(kvb + 16 + l15) * QKV_N + ch * 32 + l4 * 8];
      s0 = __builtin_amdgcn_mfma_f32_16x16x32_bf16(k0, qf[ch], s0, 0, 0, 0);
      s1 = __builtin_amdgcn_mfma_f32_16x16x32_bf16(k1, qf[ch], s1, 0, 0, 0);
    }
    // lane holds S^T[kv = kvb + st*16 + l4*4 + r][q = qb + l15]
    int qi = qb + l15;
    float pv[8];
    float tmax = -1e30f;
#pragma unroll
    for (int st = 0; st < 2; st++) {
      f32x4 s = st ? s1 : s0;
#pragma unroll
      for (int r = 0; r < 4; r++) {
        int kvi = kvb + st * 16 + l4 * 4 + r;
        float val = (kvi <= qi) ? s[r] : -1e30f;  // causal mask
        pv[st * 4 + r] = val;
        tmax = fmaxf(tmax, val);
      }
    }
    tmax = fmaxf(tmax, __shfl_xor(tmax, 16));
    tmax = fmaxf(tmax, __shfl_xor(tmax, 32));
    float mnew = fmaxf(mrun, tmax);
    float rs = 0.f;
#pragma unroll
    for (int i = 0; i < 8; i++) {
      float pe = __expf(pv[i] - mnew);
      pv[i] = pe;
      rs += pe;
    }
    rs += __shfl_xor(rs, 16);
    rs += __shfl_xor(rs, 32);
    float fsc = __expf(mrun - mnew);
    mrun = mnew;
    lsum = lsum * fsc + rs;
    // P -> LDS as [q=16][kv=32] bf16
#pragma unroll
    for (int st = 0; st < 2; st++)
#pragma unroll
      for (int r = 0; r < 4; r++)
        p_lds[l15 * 32 + st * 16 + l4 * 4 + r] = f2bf(pv[st * 4 + r]);
    __syncthreads();
    // rescale acc: acc rows are q = l4*4 + r ; fsc lives in lane q
    float fr[4];
#pragma unroll
    for (int r = 0; r < 4; r++) fr[r] = __shfl(fsc, l4 * 4 + r);
#pragma unroll
    for (int dt = 0; dt < 8; dt++)
#pragma unroll
      for (int r = 0; r < 4; r++) acc[dt][r] *= fr[r];
    // PV: A = P[q][kv] from LDS, B = V^T rows (contiguous along s)
    bf16x8 pa = *(const bf16x8*)&p_lds[l15 * 32 + l4 * 8];
#pragma unroll
    for (int dt = 0; dt < 8; dt++) {
      bf16x8 vf = *(const bf16x8*)&vbase[(size_t)(dt * 16 + l15) * Ss + kvb + l4 * 8];
      acc[dt] = __builtin_amdgcn_mfma_f32_16x16x32_bf16(pa, vf, acc[dt], 0, 0, 0);
    }
    __syncthreads();
  }
  float lr[4];
#pragma unroll
  for (int r = 0; r < 4; r++) lr[r] = __shfl(lsum, l4 * 4 + r);
#pragma unroll
  for (int dt = 0; dt < 8; dt++)
#pragma unroll
    for (int r = 0; r < 4; r++) {
      int row = qb + l4 * 4 + r;
      out[((size_t)(b * Ss) + row) * Hdim + h * HDs + dt * 16 + l15] = f2bf(acc[dt][r] / lr[r]);
    }
}

// ---------------- launcher ----------------
extern "C" void kernel_launch(void* const* d_in, const int* in_sizes, int n_in,
                              void* d_out, int out_size, void* d_ws, size_t ws_size,
                              hipStream_t stream) {
  const float* hidden = (const float*)d_in[0];
  const int* positions = (const int*)d_in[1];
  const float* wqkv = (const float*)d_in[2];
  const float* wo = (const float*)d_in[3];
  float* out = (float*)d_out;
  char* ws = (char*)d_ws;

  // workspace layout (peak 142.6 MB):
  //   ws0: hidden_bf16 [4096][4096]     (33.5 MB)  -- later reused as attn_out
  //   ws1: weightT bf16 (wqkvT then woT) (50.3 MB)
  //   ws2: qkv bf16 [4096][6144]        (50.3 MB)
  //   ws3: vt bf16 [B*NKV][128][2048]   ( 8.4 MB)
  unsigned short* hbf  = (unsigned short*)(ws);
  unsigned short* wT   = (unsigned short*)(ws + 33554432);
  unsigned short* qkvb = (unsigned short*)(ws + 83886080);
  unsigned short* vtb  = (unsigned short*)(ws + 134217728);

  // 1. hidden fp32 -> bf16
  k_f32_to_bf16<<<16384, 256, 0, stream>>>(hidden, hbf, Bb * Ss * Hdim);
  // 2. wqkv [4096][6144] -> wqkvT bf16 [6144][4096]
  k_transpose_bf16<<<dim3(QKV_N / 32, Hdim / 32), dim3(32, 8), 0, stream>>>(wqkv, wT, Hdim, QKV_N);
  // 3. qkv = hidden @ wqkv   (bf16 out)
  k_gemm<1><<<(4096 / 128) * (QKV_N / 128), 256, 0, stream>>>(hbf, wT, qkvb, 4096, QKV_N, 4096, QKV_N / 128);
  // 4. RoPE in-place (q scaled by SCALE)
  k_rope<<<dim3(10, Bb * Ss), 256, 0, stream>>>(qkvb, positions);
  // 5. V -> V^T per (b, kv head)
  k_vt<<<dim3(Ss / 32, HDs / 32, Bb * NKV), dim3(32, 8), 0, stream>>>(qkvb, vtb);
  // 6. wo [4096][4096] -> woT bf16 (reuses ws1; ordered after GEMM1 on stream)
  k_transpose_bf16<<<dim3(Hdim / 32, Hdim / 32), dim3(32, 8), 0, stream>>>(wo, wT, Hdim, Hdim);
  // 7. flash attention -> attn_out (reuses ws0)
  k_attn<<<Bb * NH * (Ss / 16), 64, 0, stream>>>(qkvb, vtb, hbf);
  // 8. out = attn_out @ wo  (fp32 out)
  k_gemm<0><<<(4096 / 128) * (4096 / 128), 256, 0, stream>>>(hbf, wT, out, 4096, 4096, 4096, 4096 / 128);
}

// Round 2
// 793.831 us; speedup vs baseline: 1.4721x; 1.4721x over previous
//
#include <hip/hip_runtime.h>
#include <hip/hip_bf16.h>
#include <stdint.h>

// Problem constants (MixtralAttention: B=2, S=2048, H=4096, 32 q-heads, 8 kv-heads, HD=128)
#define Hdim 4096
#define NH 32
#define NKV 8
#define HDs 128
#define Bb 2
#define Ss 2048
#define QKV_N 6144              // NH*HD + 2*NKV*HD
#define SCALEF 0.08838834764831845f   // 128^-0.5
// sliding window = 4096 >= S=2048  ->  pure causal mask

typedef __attribute__((ext_vector_type(4))) float f32x4;
typedef __attribute__((ext_vector_type(8))) short bf16x8;

__device__ __forceinline__ unsigned short f2bf(float f) {
  union { float f; unsigned u; } v; v.f = f;
  unsigned r = v.u + 0x7fffu + ((v.u >> 16) & 1u);   // RNE
  return (unsigned short)(r >> 16);
}
__device__ __forceinline__ float bf2f(unsigned short h) {
  union { unsigned u; float f; } v; v.u = ((unsigned)h) << 16;
  return v.f;
}

#define GLOBAL_AS(p) ((const __attribute__((address_space(1))) void*)(p))
#define LDS_AS(p)    ((__attribute__((address_space(3))) void*)(p))

// ---------------- fp32 -> bf16 elementwise (hidden_states) ----------------
__global__ void k_f32_to_bf16(const float* __restrict__ src, unsigned short* __restrict__ dst, int n) {
  int i = (blockIdx.x * blockDim.x + threadIdx.x) * 4;
  if (i >= n) return;
  f32x4 v = *(const f32x4*)(src + i);
  uint2 o;
  o.x = (unsigned)f2bf(v.x) | ((unsigned)f2bf(v.y) << 16);
  o.y = (unsigned)f2bf(v.z) | ((unsigned)f2bf(v.w) << 16);
  *(uint2*)(dst + i) = o;
}

// ---------------- fp32 [K][N] -> bf16 [N][K] tile transpose (weights) ----------------
__global__ void k_transpose_bf16(const float* __restrict__ src, unsigned short* __restrict__ dst,
                                 int K, int N) {
  __shared__ unsigned short tile[32][33];
  int n0 = blockIdx.x * 32, k0 = blockIdx.y * 32;
  int tx = threadIdx.x, ty0 = threadIdx.y;
#pragma unroll
  for (int i = 0; i < 4; i++) {
    int ty = ty0 + i * 8;
    tile[ty][tx] = f2bf(src[(size_t)(k0 + ty) * N + n0 + tx]);
  }
  __syncthreads();
#pragma unroll
  for (int i = 0; i < 4; i++) {
    int ty = ty0 + i * 8;
    dst[(size_t)(n0 + ty) * K + k0 + tx] = tile[tx][ty];
  }
}

// ---------------- bf16 GEMM: C[M][N] = A[M][K] * Bt[N][K]^T  (m97-style 128x128, BK=32) ----------
template <int OUT_BF16>
__global__ __launch_bounds__(256) void k_gemm(const unsigned short* __restrict__ A,
                                              const unsigned short* __restrict__ Bt,
                                              void* __restrict__ C,
                                              int M, int N, int K, int nbn) {
  __shared__ __align__(16) unsigned short As[128 * 32];
  __shared__ __align__(16) unsigned short Bs[128 * 32];
  int bn = blockIdx.x % nbn, bm = blockIdx.x / nbn;
  int t = threadIdx.x;
  int lane = t & 63, w = t >> 6;
  int wm = w >> 1, wn = w & 1;
  int l15 = lane & 15, l4 = lane >> 4;

  f32x4 zero = {0.f, 0.f, 0.f, 0.f};
  f32x4 acc[4][4];
#pragma unroll
  for (int m = 0; m < 4; m++)
#pragma unroll
    for (int n = 0; n < 4; n++) acc[m][n] = zero;

  size_t arow0 = (size_t)bm * 128 * K;
  size_t brow0 = (size_t)bn * 128 * K;
  int srow = t >> 2;            // 0..63
  int sko = (t & 3) * 8;        // 0,8,16,24

  for (int ks = 0; ks < K; ks += 32) {
#pragma unroll
    for (int c = 0; c < 2; c++) {
      int row = c * 64 + srow;
      const unsigned short* ga = A + arow0 + (size_t)row * K + ks + sko;
      const unsigned short* gb = Bt + brow0 + (size_t)row * K + ks + sko;
      __builtin_amdgcn_global_load_lds(GLOBAL_AS(ga), LDS_AS(As + c * 2048 + w * 512), 16, 0, 0);
      __builtin_amdgcn_global_load_lds(GLOBAL_AS(gb), LDS_AS(Bs + c * 2048 + w * 512), 16, 0, 0);
    }
    __syncthreads();
    bf16x8 af[4], bfr[4];
#pragma unroll
    for (int m = 0; m < 4; m++)
      af[m] = *(const bf16x8*)&As[(wm * 64 + m * 16 + l15) * 32 + l4 * 8];
#pragma unroll
    for (int n = 0; n < 4; n++)
      bfr[n] = *(const bf16x8*)&Bs[(wn * 64 + n * 16 + l15) * 32 + l4 * 8];
#pragma unroll
    for (int m = 0; m < 4; m++)
#pragma unroll
      for (int n = 0; n < 4; n++)
        acc[m][n] = __builtin_amdgcn_mfma_f32_16x16x32_bf16(af[m], bfr[n], acc[m][n], 0, 0, 0);
    __syncthreads();
  }
  // C/D layout: col = lane&15, row = (lane>>4)*4 + reg   [verified m89/m91]
#pragma unroll
  for (int m = 0; m < 4; m++)
#pragma unroll
    for (int n = 0; n < 4; n++) {
      int col = bn * 128 + wn * 64 + n * 16 + l15;
#pragma unroll
      for (int r = 0; r < 4; r++) {
        int row = bm * 128 + wm * 64 + m * 16 + l4 * 4 + r;
        float v = acc[m][n][r];
        if (OUT_BF16)
          ((unsigned short*)C)[(size_t)row * N + col] = f2bf(v);
        else
          ((float*)C)[(size_t)row * N + col] = v;
      }
    }
}

// ---------------- RoPE (interleaved pairs) in-place on bf16 qkv; folds SCALE into q ------------
__global__ void k_rope(unsigned short* __restrict__ qkv, const int* __restrict__ pos) {
  int bs = blockIdx.y;                       // b*S + s
  int t = threadIdx.x;                       // 256
  int head = blockIdx.x * 4 + (t >> 6);      // 0..39 (0-31 q, 32-39 k)
  int p = t & 63;                            // pair index
  int col;
  float scale;
  if (head < NH) { col = head * HDs + 2 * p; scale = SCALEF; }
  else           { col = NH * HDs + (head - NH) * HDs + 2 * p; scale = 1.f; }
  size_t idx = (size_t)bs * QKV_N + col;
  float x0 = bf2f(qkv[idx]), x1 = bf2f(qkv[idx + 1]);
  float position = (float)pos[bs];
  // inv_freq = 10000^(-2p/128) = exp2(-p * 2*log2(10000)/128)
  float inv_freq = exp2f((float)p * -0.2076205059304601f);
  float ang = position * inv_freq;
  float sv, cv;
  sincosf(ang, &sv, &cv);
  float o0 = (x0 * cv - x1 * sv) * scale;
  float o1 = (x1 * cv + x0 * sv) * scale;
  qkv[idx]     = f2bf(o0);
  qkv[idx + 1] = f2bf(o1);
}

// ---------------- V repack: qkv v-part [s][d] -> vt[b][kv][d][s] (bf16 tile transpose) ---------
__global__ void k_vt(const unsigned short* __restrict__ qkv, unsigned short* __restrict__ vt) {
  __shared__ unsigned short tile[32][33];
  int bkv = blockIdx.z;                 // b*NKV + kvh
  int d0 = blockIdx.y * 32;
  int s0 = blockIdx.x * 32;
  int b = bkv >> 3, kvh = bkv & 7;
  int tx = threadIdx.x, ty0 = threadIdx.y;
  const unsigned short* src = qkv + (size_t)b * Ss * QKV_N + NH * HDs + NKV * HDs + kvh * HDs;
#pragma unroll
  for (int i = 0; i < 4; i++) {
    int ty = ty0 + i * 8;
    tile[ty][tx] = src[(size_t)(s0 + ty) * QKV_N + d0 + tx];
  }
  __syncthreads();
  unsigned short* dst = vt + (size_t)bkv * HDs * Ss;
#pragma unroll
  for (int i = 0; i < 4; i++) {
    int ty = ty0 + i * 8;
    dst[(size_t)(d0 + ty) * Ss + s0 + tx] = tile[tx][ty];
  }
}

// ---------------- Flash attention v2: 4 waves/block, 128 q rows/block, KV staged in LDS -------
// Per 64-kv step: K tile [64][128] and V^T tile [128][64] in LDS (XOR-swizzled via
// pre-swizzled global source, rule #21), double-buffered. Each wave owns 32 q rows
// (2x 16-row sub-tiles). Swapped QK^T (mfma(K,Q)) -> softmax reduce is 2 shfl_xor.
// P round-trips through a per-wave swizzled LDS buffer (same-wave RAW, no barrier).
__global__ __launch_bounds__(256, 2) void k_attn(const unsigned short* __restrict__ qkv,
                                                 const unsigned short* __restrict__ vt,
                                                 unsigned short* __restrict__ out) {
  __shared__ __align__(16) unsigned short Ks[2][64 * 128];   // 32 KB
  __shared__ __align__(16) unsigned short Vs[2][128 * 64];   // 32 KB
  __shared__ __align__(16) unsigned short Ps[4][32 * 64];    // 16 KB (per-wave P)

  int bid = blockIdx.x;
  int qc = bid & 15;            // 16 q-chunks of 128 rows
  int h = (bid >> 4) & 31;
  int b = bid >> 9;
  int kvh = h >> 2;             // GROUP = 4
  int t = threadIdx.x;
  int w = t >> 6, lane = t & 63;
  int l15 = lane & 15, l4 = lane >> 4;
  int qb0 = qc * 128;
  int qw = qb0 + w * 32;        // this wave's first q row

  const unsigned short* kbase = qkv + (size_t)b * Ss * QKV_N + NH * HDs + (size_t)kvh * HDs;
  const unsigned short* vbase = vt + ((size_t)(b * NKV + kvh)) * HDs * Ss;

  // Q fragments (B-operand of mfma(K,Q)): Q[qw + qt*16 + l15][ch*32 + l4*8 + e]
  bf16x8 qf[2][4];
#pragma unroll
  for (int qt = 0; qt < 2; qt++)
#pragma unroll
    for (int ch = 0; ch < 4; ch++)
      qf[qt][ch] = *(const bf16x8*)&qkv[((size_t)(b * Ss) + qw + qt * 16 + l15) * QKV_N +
                                        (size_t)h * HDs + ch * 32 + l4 * 8];

  f32x4 zero = {0.f, 0.f, 0.f, 0.f};
  f32x4 acc[2][8];
#pragma unroll
  for (int qt = 0; qt < 2; qt++)
#pragma unroll
    for (int dt = 0; dt < 8; dt++) acc[qt][dt] = zero;
  float mrun[2] = {-1e30f, -1e30f}, lsum[2] = {0.f, 0.f};

  int nkv = qc * 2 + 2;         // 64-row kv blocks covering kv <= qb0+127

  // stage K[64][128] + V^T[128][64] for kv block kv_ into buffer bufi.
  // LDS dest is linear (wave-uniform base + lane*16); swizzle achieved by XOR on the
  // global source column slot (involution), so swizzled ds_reads see logical data.
  auto stage = [&](int bufi, int kv_) {
#pragma unroll
    for (int r_ = 0; r_ < 4; r_++) {
      int krow = r_ * 16 + w * 4 + (lane >> 4);
      int kls = (lane & 15) ^ (krow & 7);
      __builtin_amdgcn_global_load_lds(GLOBAL_AS(kbase + (size_t)(kv_ + krow) * QKV_N + kls * 8),
                                       LDS_AS(&Ks[bufi][r_ * 2048 + w * 512]), 16, 0, 0);
    }
#pragma unroll
    for (int r_ = 0; r_ < 4; r_++) {
      int vrow = r_ * 32 + w * 8 + (lane >> 3);
      int vls = (lane & 7) ^ (vrow & 7);
      __builtin_amdgcn_global_load_lds(GLOBAL_AS(vbase + (size_t)vrow * Ss + kv_ + vls * 8),
                                       LDS_AS(&Vs[bufi][r_ * 2048 + w * 512]), 16, 0, 0);
    }
  };

  stage(0, 0);
  for (int it = 0; it < nkv; it++) {
    int kvb = it * 64;
    if (it + 1 < nkv) stage((it + 1) & 1, kvb + 64);
    __syncthreads();   // drains vmcnt -> buffer (it&1) ready for all waves
    if (kvb <= qw + 31) {
      const unsigned short* Kb = Ks[it & 1];
      const unsigned short* Vb = Vs[it & 1];
      unsigned short* Pw = Ps[w];
      bool act0 = (kvb <= qw + 15);   // qt=1 always active here

      // ---- QK^T: S^T[kv][q] = mfma(A=K, B=Q), accumulate over 4 d-chunks ----
      f32x4 sacc[2][4];
#pragma unroll
      for (int qt = 0; qt < 2; qt++)
#pragma unroll
        for (int kt2 = 0; kt2 < 4; kt2++) sacc[qt][kt2] = zero;
#pragma unroll
      for (int kt2 = 0; kt2 < 4; kt2++) {
        int row = kt2 * 16 + l15;
#pragma unroll
        for (int ch = 0; ch < 4; ch++) {
          int ps = (ch * 4 + l4) ^ (row & 7);
          bf16x8 kf = *(const bf16x8*)&Kb[row * 128 + ps * 8];
          if (act0) sacc[0][kt2] = __builtin_amdgcn_mfma_f32_16x16x32_bf16(kf, qf[0][ch], sacc[0][kt2], 0, 0, 0);
          sacc[1][kt2] = __builtin_amdgcn_mfma_f32_16x16x32_bf16(kf, qf[1][ch], sacc[1][kt2], 0, 0, 0);
        }
      }

      // ---- per-sub-tile online softmax + P write + O rescale ----
#pragma unroll
      for (int qt = 0; qt < 2; qt++) {
        if (qt == 0 && !act0) continue;
        int qi = qw + qt * 16 + l15;   // this lane's q column
        float pv[16];
        float tmax = -1e30f;
#pragma unroll
        for (int kt2 = 0; kt2 < 4; kt2++)
#pragma unroll
          for (int r = 0; r < 4; r++) {
            int kvi = kvb + kt2 * 16 + l4 * 4 + r;
            float v = sacc[qt][kt2][r];
            v = (kvi <= qi) ? v : -1e30f;
            pv[kt2 * 4 + r] = v;
            tmax = fmaxf(tmax, v);
          }
        tmax = fmaxf(tmax, __shfl_xor(tmax, 16));
        tmax = fmaxf(tmax, __shfl_xor(tmax, 32));
        float mnew = fmaxf(mrun[qt], tmax);
        float rs = 0.f;
#pragma unroll
        for (int i = 0; i < 16; i++) {
          pv[i] = __expf(pv[i] - mnew);
          rs += pv[i];
        }
        rs += __shfl_xor(rs, 16);
        rs += __shfl_xor(rs, 32);
        float fsc = __expf(mrun[qt] - mnew);
        mrun[qt] = mnew;
        lsum[qt] = lsum[qt] * fsc + rs;
        // P^T -> P: write P[q = qt*16+l15][kv], u32-packed pairs, swizzled slots
        int prow = qt * 16 + l15;
#pragma unroll
        for (int kt2 = 0; kt2 < 4; kt2++)
#pragma unroll
          for (int rp = 0; rp < 2; rp++) {
            int kv = kt2 * 16 + l4 * 4 + rp * 2;
            int ps = (kv >> 3) ^ (l15 & 7);
            unsigned u = (unsigned)f2bf(pv[kt2 * 4 + rp * 2]) |
                         ((unsigned)f2bf(pv[kt2 * 4 + rp * 2 + 1]) << 16);
            *(unsigned*)&Pw[prow * 64 + ps * 8 + (kv & 7)] = u;
          }
        // rescale O accumulator (rows q = l4*4 + r)
        float fr[4];
#pragma unroll
        for (int r = 0; r < 4; r++) fr[r] = __shfl(fsc, l4 * 4 + r);
#pragma unroll
        for (int dt = 0; dt < 8; dt++)
#pragma unroll
          for (int r = 0; r < 4; r++) acc[qt][dt][r] *= fr[r];
      }

      // ---- PV: O[q][d] += P[q][kv] * V^T[d][kv] ----
#pragma unroll
      for (int kc = 0; kc < 2; kc++) {
        int psp = (kc * 4 + l4) ^ (l15 & 7);
        bf16x8 pa0 = *(const bf16x8*)&Pw[l15 * 64 + psp * 8];
        bf16x8 pa1 = *(const bf16x8*)&Pw[(16 + l15) * 64 + psp * 8];
#pragma unroll
        for (int dt = 0; dt < 8; dt++) {
          int d = dt * 16 + l15;
          int ps = (kc * 4 + l4) ^ (d & 7);
          bf16x8 vf = *(const bf16x8*)&Vb[d * 64 + ps * 8];
          if (act0) acc[0][dt] = __builtin_amdgcn_mfma_f32_16x16x32_bf16(pa0, vf, acc[0][dt], 0, 0, 0);
          acc[1][dt] = __builtin_amdgcn_mfma_f32_16x16x32_bf16(pa1, vf, acc[1][dt], 0, 0, 0);
        }
      }
    }
    __syncthreads();   // all reads of buffer (it&1) done -> next iter may overwrite
  }

  // ---- epilogue: normalize and store ----
#pragma unroll
  for (int qt = 0; qt < 2; qt++) {
    float lr[4];
#pragma unroll
    for (int r = 0; r < 4; r++) lr[r] = __shfl(lsum[qt], l4 * 4 + r);
#pragma unroll
    for (int dt = 0; dt < 8; dt++)
#pragma unroll
      for (int r = 0; r < 4; r++) {
        int row = qw + qt * 16 + l4 * 4 + r;
        out[((size_t)(b * Ss) + row) * Hdim + (size_t)h * HDs + dt * 16 + l15] =
            f2bf(acc[qt][dt][r] / lr[r]);
      }
  }
}

// ---------------- launcher ----------------
extern "C" void kernel_launch(void* const* d_in, const int* in_sizes, int n_in,
                              void* d_out, int out_size, void* d_ws, size_t ws_size,
                              hipStream_t stream) {
  const float* hidden = (const float*)d_in[0];
  const int* positions = (const int*)d_in[1];
  const float* wqkv = (const float*)d_in[2];
  const float* wo = (const float*)d_in[3];
  float* out = (float*)d_out;
  char* ws = (char*)d_ws;

  // workspace layout (peak 142.6 MB):
  //   ws0: hidden_bf16 [4096][4096]     (33.5 MB)  -- later reused as attn_out
  //   ws1: weightT bf16 (wqkvT then woT) (50.3 MB)
  //   ws2: qkv bf16 [4096][6144]        (50.3 MB)
  //   ws3: vt bf16 [B*NKV][128][2048]   ( 8.4 MB)
  unsigned short* hbf  = (unsigned short*)(ws);
  unsigned short* wT   = (unsigned short*)(ws + 33554432);
  unsigned short* qkvb = (unsigned short*)(ws + 83886080);
  unsigned short* vtb  = (unsigned short*)(ws + 134217728);

  // 1. hidden fp32 -> bf16
  k_f32_to_bf16<<<16384, 256, 0, stream>>>(hidden, hbf, Bb * Ss * Hdim);
  // 2. wqkv [4096][6144] -> wqkvT bf16 [6144][4096]
  k_transpose_bf16<<<dim3(QKV_N / 32, Hdim / 32), dim3(32, 8), 0, stream>>>(wqkv, wT, Hdim, QKV_N);
  // 3. qkv = hidden @ wqkv   (bf16 out)
  k_gemm<1><<<(4096 / 128) * (QKV_N / 128), 256, 0, stream>>>(hbf, wT, qkvb, 4096, QKV_N, 4096, QKV_N / 128);
  // 4. RoPE in-place (q scaled by SCALE)
  k_rope<<<dim3(10, Bb * Ss), 256, 0, stream>>>(qkvb, positions);
  // 5. V -> V^T per (b, kv head)
  k_vt<<<dim3(Ss / 32, HDs / 32, Bb * NKV), dim3(32, 8), 0, stream>>>(qkvb, vtb);
  // 6. wo [4096][4096] -> woT bf16 (reuses ws1; ordered after GEMM1 on stream)
  k_transpose_bf16<<<dim3(Hdim / 32, Hdim / 32), dim3(32, 8), 0, stream>>>(wo, wT, Hdim, Hdim);
  // 7. flash attention v2 -> attn_out (reuses ws0)
  k_attn<<<Bb * NH * (Ss / 128), 256, 0, stream>>>(qkvb, vtb, hbf);
  // 8. out = attn_out @ wo  (fp32 out)
  k_gemm<0><<<(4096 / 128) * (4096 / 128), 256, 0, stream>>>(hbf, wT, out, 4096, 4096, 4096, 4096 / 128);
}

// Round 4
// 691.041 us; speedup vs baseline: 1.6911x; 1.1487x over previous
//
#include <hip/hip_runtime.h>
#include <hip/hip_bf16.h>
#include <stdint.h>

// Problem constants (MixtralAttention: B=2, S=2048, H=4096, 32 q-heads, 8 kv-heads, HD=128)
#define Hdim 4096
#define NH 32
#define NKV 8
#define HDs 128
#define Bb 2
#define Ss 2048
#define QKV_N 6144              // NH*HD + 2*NKV*HD
#define SCALEF 0.08838834764831845f   // 128^-0.5
// sliding window = 4096 >= S=2048  ->  pure causal mask

typedef __attribute__((ext_vector_type(4))) float f32x4;
typedef __attribute__((ext_vector_type(8))) short bf16x8;

__device__ __forceinline__ unsigned short f2bf(float f) {
  union { float f; unsigned u; } v; v.f = f;
  unsigned r = v.u + 0x7fffu + ((v.u >> 16) & 1u);   // RNE
  return (unsigned short)(r >> 16);
}
__device__ __forceinline__ float bf2f(unsigned short h) {
  union { unsigned u; float f; } v; v.u = ((unsigned)h) << 16;
  return v.f;
}

#define GLOBAL_AS(p) ((const __attribute__((address_space(1))) void*)(p))
#define LDS_AS(p)    ((__attribute__((address_space(3))) void*)(p))

// ---------------- fp32 -> bf16 elementwise (hidden_states) ----------------
__global__ void k_f32_to_bf16(const float* __restrict__ src, unsigned short* __restrict__ dst, int n) {
  int i = (blockIdx.x * blockDim.x + threadIdx.x) * 4;
  if (i >= n) return;
  f32x4 v = *(const f32x4*)(src + i);
  uint2 o;
  o.x = (unsigned)f2bf(v.x) | ((unsigned)f2bf(v.y) << 16);
  o.y = (unsigned)f2bf(v.z) | ((unsigned)f2bf(v.w) << 16);
  *(uint2*)(dst + i) = o;
}

// ---------------- fp32 [K][N] -> bf16 [N][K] tile transpose (weights) ----------------
__global__ void k_transpose_bf16(const float* __restrict__ src, unsigned short* __restrict__ dst,
                                 int K, int N) {
  __shared__ unsigned short tile[32][33];
  int n0 = blockIdx.x * 32, k0 = blockIdx.y * 32;
  int tx = threadIdx.x, ty0 = threadIdx.y;
#pragma unroll
  for (int i = 0; i < 4; i++) {
    int ty = ty0 + i * 8;
    tile[ty][tx] = f2bf(src[(size_t)(k0 + ty) * N + n0 + tx]);
  }
  __syncthreads();
#pragma unroll
  for (int i = 0; i < 4; i++) {
    int ty = ty0 + i * 8;
    dst[(size_t)(n0 + ty) * K + k0 + tx] = tile[tx][ty];
  }
}

// ---------------- bf16 GEMM, 8-phase counted-vmcnt pipeline ----------------
// C[M][N] = A[M][K] * Bt[N][K]^T.  BM=256, BN=128, BK=64, 512 threads (8 waves, 4M x 2N,
// 64x64 per wave).  3-deep K-tile LDS rotation (buf kt%3, 144 KB total): while computing
// K-tile kt (2 phases of 16 MFMA each), stage K-tile kt+2 into buffer (kt+2)%3 -- that
// buffer was last read during K-tile kt-1, which ended at the barrier before these issues.
// vmcnt(6) once per K-tile drains exactly the NEXT K-tile's 6 loads while keeping the
// following K-tile's 6 loads in flight across barriers (T3+T4).  LDS slot-swizzle
// (slot ^= row&7) applied via pre-swizzled global source (linear DMA dest, rule #21).
template <int OUT_BF16>
__global__ __launch_bounds__(512) void k_gemm8(const unsigned short* __restrict__ A,
                                               const unsigned short* __restrict__ Bt,
                                               void* __restrict__ C,
                                               int M, int N, int K, int nbn) {
  __shared__ __align__(16) unsigned short As[3][256 * 64];   // 96 KB
  __shared__ __align__(16) unsigned short Bs[3][128 * 64];   // 48 KB

  // XCD-aware bijective block swizzle (grid % 8 == 0 for all our launches)
  int nwg = gridDim.x;
  int orig = blockIdx.x;
  int wg = (orig & 7) * (nwg >> 3) + (orig >> 3);
  int bm = wg / nbn, bn = wg % nbn;

  int t = threadIdx.x, w = t >> 6, lane = t & 63;
  int wm = w >> 1, wn = w & 1;        // wave tile: rows wm*64, cols wn*64
  int l15 = lane & 15, l4 = lane >> 4;

  const unsigned short* Ag = A + (size_t)(bm * 256) * K;
  const unsigned short* Bg = Bt + (size_t)(bn * 128) * K;

  // staging geometry: one global_load_lds inst = 512 thr x 16 B = 8 KB = 64 rows x 128 B.
  // dest linear: row-in-chunk = w*8 + lane/8, physical slot = lane&7 ;
  // source pre-swizzled: logical k-slot = (lane&7) ^ ((lane>>3)&7)   (= phys ^ (row&7))
  int srow = w * 8 + (lane >> 3);
  int sloff = ((lane & 7) ^ ((lane >> 3) & 7)) * 8;

  f32x4 zero = {0.f, 0.f, 0.f, 0.f};
  f32x4 acc[4][4];
#pragma unroll
  for (int m = 0; m < 4; m++)
#pragma unroll
    for (int n = 0; n < 4; n++) acc[m][n] = zero;

  int NKT = K >> 6;

  // stage half h (h=0/1) of K-tile kt into buffer buf: A rows [h*128, h*128+128) (2 insts)
  // + B rows [h*64, h*64+64) (1 inst)
  auto stage_half = [&](int buf, int kt, int h) {
#pragma unroll
    for (int i2 = 0; i2 < 2; i2++) {
      int row = h * 128 + i2 * 64 + srow;
      __builtin_amdgcn_global_load_lds(GLOBAL_AS(Ag + (size_t)row * K + kt * 64 + sloff),
                                       LDS_AS(&As[buf][h * 8192 + i2 * 4096 + w * 512]), 16, 0, 0);
    }
    {
      int row = h * 64 + srow;
      __builtin_amdgcn_global_load_lds(GLOBAL_AS(Bg + (size_t)row * K + kt * 64 + sloff),
                                       LDS_AS(&Bs[buf][h * 4096 + w * 512]), 16, 0, 0);
    }
  };

  // prologue: Kt0 -> buf0 (6 loads), Kt1 -> buf1 (6 loads); drain Kt0, keep Kt1 in flight
  stage_half(0, 0, 0); stage_half(0, 0, 1);
  stage_half(1, 1, 0); stage_half(1, 1, 1);
  asm volatile("s_waitcnt vmcnt(6)" ::: "memory");
  __builtin_amdgcn_s_barrier();

  for (int kt = 0; kt < NKT; kt++) {
    int cb = kt % 3;
    const unsigned short* Abp = As[cb];
    const unsigned short* Bbp = Bs[cb];
#pragma unroll
    for (int q = 0; q < 2; q++) {
      // ---- ds-load register subtile: 4 A-frags + 4 B-frags (kstep q) ----
      bf16x8 af[4], bf[4];
#pragma unroll
      for (int m = 0; m < 4; m++) {
        int row = wm * 64 + m * 16 + l15;
        int ph = (q * 4 + l4) ^ (row & 7);
        af[m] = *(const bf16x8*)&Abp[row * 64 + ph * 8];
      }
#pragma unroll
      for (int n = 0; n < 4; n++) {
        int row = wn * 64 + n * 16 + l15;
        int ph = (q * 4 + l4) ^ (row & 7);
        bf[n] = *(const bf16x8*)&Bbp[row * 64 + ph * 8];
      }
      // ---- stage half q of K-tile kt+2 (buffer freed at end of kt-1) ----
      if (kt + 2 < NKT) stage_half((kt + 2) % 3, kt + 2, q);
      __builtin_amdgcn_s_barrier();
      asm volatile("s_waitcnt lgkmcnt(0)" ::: "memory");
      __builtin_amdgcn_sched_barrier(0);
      __builtin_amdgcn_s_setprio(1);
#pragma unroll
      for (int m = 0; m < 4; m++)
#pragma unroll
        for (int n = 0; n < 4; n++)
          acc[m][n] = __builtin_amdgcn_mfma_f32_16x16x32_bf16(af[m], bf[n], acc[m][n], 0, 0, 0);
      __builtin_amdgcn_s_setprio(0);
      if (q == 1) {
        // drain exactly the next K-tile's 6 loads; keep kt+2's 6 in flight (never 0 mid-loop)
        if (kt + 2 < NKT) asm volatile("s_waitcnt vmcnt(6)" ::: "memory");
        else              asm volatile("s_waitcnt vmcnt(0)" ::: "memory");
      }
      __builtin_amdgcn_s_barrier();
    }
  }

  // epilogue: C/D layout col=lane&15, row=(lane>>4)*4+reg  [verified m89/m91]
#pragma unroll
  for (int m = 0; m < 4; m++)
#pragma unroll
    for (int n = 0; n < 4; n++) {
      int col = bn * 128 + wn * 64 + n * 16 + l15;
#pragma unroll
      for (int r = 0; r < 4; r++) {
        int row = bm * 256 + wm * 64 + m * 16 + l4 * 4 + r;
        float v = acc[m][n][r];
        if (OUT_BF16)
          ((unsigned short*)C)[(size_t)row * N + col] = f2bf(v);
        else
          ((float*)C)[(size_t)row * N + col] = v;
      }
    }
}

// ---------------- RoPE (interleaved pairs) in-place on bf16 qkv; folds SCALE into q ------------
__global__ void k_rope(unsigned short* __restrict__ qkv, const int* __restrict__ pos) {
  int bs = blockIdx.y;                       // b*S + s
  int t = threadIdx.x;                       // 256
  int head = blockIdx.x * 4 + (t >> 6);      // 0..39 (0-31 q, 32-39 k)
  int p = t & 63;                            // pair index
  int col;
  float scale;
  if (head < NH) { col = head * HDs + 2 * p; scale = SCALEF; }
  else           { col = NH * HDs + (head - NH) * HDs + 2 * p; scale = 1.f; }
  size_t idx = (size_t)bs * QKV_N + col;
  float x0 = bf2f(qkv[idx]), x1 = bf2f(qkv[idx + 1]);
  float position = (float)pos[bs];
  // inv_freq = 10000^(-2p/128) = exp2(-p * 2*log2(10000)/128)
  float inv_freq = exp2f((float)p * -0.2076205059304601f);
  float ang = position * inv_freq;
  float sv, cv;
  sincosf(ang, &sv, &cv);
  float o0 = (x0 * cv - x1 * sv) * scale;
  float o1 = (x1 * cv + x0 * sv) * scale;
  qkv[idx]     = f2bf(o0);
  qkv[idx + 1] = f2bf(o1);
}

// ---------------- V repack: qkv v-part [s][d] -> vt[b][kv][d][s] (bf16 tile transpose) ---------
__global__ void k_vt(const unsigned short* __restrict__ qkv, unsigned short* __restrict__ vt) {
  __shared__ unsigned short tile[32][33];
  int bkv = blockIdx.z;                 // b*NKV + kvh
  int d0 = blockIdx.y * 32;
  int s0 = blockIdx.x * 32;
  int b = bkv >> 3, kvh = bkv & 7;
  int tx = threadIdx.x, ty0 = threadIdx.y;
  const unsigned short* src = qkv + (size_t)b * Ss * QKV_N + NH * HDs + NKV * HDs + kvh * HDs;
#pragma unroll
  for (int i = 0; i < 4; i++) {
    int ty = ty0 + i * 8;
    tile[ty][tx] = src[(size_t)(s0 + ty) * QKV_N + d0 + tx];
  }
  __syncthreads();
  unsigned short* dst = vt + (size_t)bkv * HDs * Ss;
#pragma unroll
  for (int i = 0; i < 4; i++) {
    int ty = ty0 + i * 8;
    dst[(size_t)(d0 + ty) * Ss + s0 + tx] = tile[tx][ty];
  }
}

// ---------------- Flash attention v2: 4 waves/block, 128 q rows/block, KV staged in LDS -------
__global__ __launch_bounds__(256, 2) void k_attn(const unsigned short* __restrict__ qkv,
                                                 const unsigned short* __restrict__ vt,
                                                 unsigned short* __restrict__ out) {
  __shared__ __align__(16) unsigned short Ks[2][64 * 128];   // 32 KB
  __shared__ __align__(16) unsigned short Vs[2][128 * 64];   // 32 KB
  __shared__ __align__(16) unsigned short Ps[4][32 * 64];    // 16 KB (per-wave P)

  int bid = blockIdx.x;
  int qc = bid & 15;            // 16 q-chunks of 128 rows
  int h = (bid >> 4) & 31;
  int b = bid >> 9;
  int kvh = h >> 2;             // GROUP = 4
  int t = threadIdx.x;
  int w = t >> 6, lane = t & 63;
  int l15 = lane & 15, l4 = lane >> 4;
  int qb0 = qc * 128;
  int qw = qb0 + w * 32;        // this wave's first q row

  const unsigned short* kbase = qkv + (size_t)b * Ss * QKV_N + NH * HDs + (size_t)kvh * HDs;
  const unsigned short* vbase = vt + ((size_t)(b * NKV + kvh)) * HDs * Ss;

  bf16x8 qf[2][4];
#pragma unroll
  for (int qt = 0; qt < 2; qt++)
#pragma unroll
    for (int ch = 0; ch < 4; ch++)
      qf[qt][ch] = *(const bf16x8*)&qkv[((size_t)(b * Ss) + qw + qt * 16 + l15) * QKV_N +
                                        (size_t)h * HDs + ch * 32 + l4 * 8];

  f32x4 zero = {0.f, 0.f, 0.f, 0.f};
  f32x4 acc[2][8];
#pragma unroll
  for (int qt = 0; qt < 2; qt++)
#pragma unroll
    for (int dt = 0; dt < 8; dt++) acc[qt][dt] = zero;
  float mrun[2] = {-1e30f, -1e30f}, lsum[2] = {0.f, 0.f};

  int nkv = qc * 2 + 2;         // 64-row kv blocks covering kv <= qb0+127

  auto stage = [&](int bufi, int kv_) {
#pragma unroll
    for (int r_ = 0; r_ < 4; r_++) {
      int krow = r_ * 16 + w * 4 + (lane >> 4);
      int kls = (lane & 15) ^ (krow & 7);
      __builtin_amdgcn_global_load_lds(GLOBAL_AS(kbase + (size_t)(kv_ + krow) * QKV_N + kls * 8),
                                       LDS_AS(&Ks[bufi][r_ * 2048 + w * 512]), 16, 0, 0);
    }
#pragma unroll
    for (int r_ = 0; r_ < 4; r_++) {
      int vrow = r_ * 32 + w * 8 + (lane >> 3);
      int vls = (lane & 7) ^ (vrow & 7);
      __builtin_amdgcn_global_load_lds(GLOBAL_AS(vbase + (size_t)vrow * Ss + kv_ + vls * 8),
                                       LDS_AS(&Vs[bufi][r_ * 2048 + w * 512]), 16, 0, 0);
    }
  };

  stage(0, 0);
  for (int it = 0; it < nkv; it++) {
    int kvb = it * 64;
    if (it + 1 < nkv) stage((it + 1) & 1, kvb + 64);
    __syncthreads();
    if (kvb <= qw + 31) {
      const unsigned short* Kb = Ks[it & 1];
      const unsigned short* Vb = Vs[it & 1];
      unsigned short* Pw = Ps[w];
      bool act0 = (kvb <= qw + 15);

      f32x4 sacc[2][4];
#pragma unroll
      for (int qt = 0; qt < 2; qt++)
#pragma unroll
        for (int kt2 = 0; kt2 < 4; kt2++) sacc[qt][kt2] = zero;
#pragma unroll
      for (int kt2 = 0; kt2 < 4; kt2++) {
        int row = kt2 * 16 + l15;
#pragma unroll
        for (int ch = 0; ch < 4; ch++) {
          int ps = (ch * 4 + l4) ^ (row & 7);
          bf16x8 kf = *(const bf16x8*)&Kb[row * 128 + ps * 8];
          if (act0) sacc[0][kt2] = __builtin_amdgcn_mfma_f32_16x16x32_bf16(kf, qf[0][ch], sacc[0][kt2], 0, 0, 0);
          sacc[1][kt2] = __builtin_amdgcn_mfma_f32_16x16x32_bf16(kf, qf[1][ch], sacc[1][kt2], 0, 0, 0);
        }
      }

#pragma unroll
      for (int qt = 0; qt < 2; qt++) {
        if (qt == 0 && !act0) continue;
        int qi = qw + qt * 16 + l15;
        float pv[16];
        float tmax = -1e30f;
#pragma unroll
        for (int kt2 = 0; kt2 < 4; kt2++)
#pragma unroll
          for (int r = 0; r < 4; r++) {
            int kvi = kvb + kt2 * 16 + l4 * 4 + r;
            float v = sacc[qt][kt2][r];
            v = (kvi <= qi) ? v : -1e30f;
            pv[kt2 * 4 + r] = v;
            tmax = fmaxf(tmax, v);
          }
        tmax = fmaxf(tmax, __shfl_xor(tmax, 16));
        tmax = fmaxf(tmax, __shfl_xor(tmax, 32));
        float mnew = fmaxf(mrun[qt], tmax);
        float rs = 0.f;
#pragma unroll
        for (int i = 0; i < 16; i++) {
          pv[i] = __expf(pv[i] - mnew);
          rs += pv[i];
        }
        rs += __shfl_xor(rs, 16);
        rs += __shfl_xor(rs, 32);
        float fsc = __expf(mrun[qt] - mnew);
        mrun[qt] = mnew;
        lsum[qt] = lsum[qt] * fsc + rs;
        int prow = qt * 16 + l15;
#pragma unroll
        for (int kt2 = 0; kt2 < 4; kt2++)
#pragma unroll
          for (int rp = 0; rp < 2; rp++) {
            int kv = kt2 * 16 + l4 * 4 + rp * 2;
            int ps = (kv >> 3) ^ (l15 & 7);
            unsigned u = (unsigned)f2bf(pv[kt2 * 4 + rp * 2]) |
                         ((unsigned)f2bf(pv[kt2 * 4 + rp * 2 + 1]) << 16);
            *(unsigned*)&Pw[prow * 64 + ps * 8 + (kv & 7)] = u;
          }
        float fr[4];
#pragma unroll
        for (int r = 0; r < 4; r++) fr[r] = __shfl(fsc, l4 * 4 + r);
#pragma unroll
        for (int dt = 0; dt < 8; dt++)
#pragma unroll
          for (int r = 0; r < 4; r++) acc[qt][dt][r] *= fr[r];
      }

#pragma unroll
      for (int kc = 0; kc < 2; kc++) {
        int psp = (kc * 4 + l4) ^ (l15 & 7);
        bf16x8 pa0 = *(const bf16x8*)&Pw[l15 * 64 + psp * 8];
        bf16x8 pa1 = *(const bf16x8*)&Pw[(16 + l15) * 64 + psp * 8];
#pragma unroll
        for (int dt = 0; dt < 8; dt++) {
          int d = dt * 16 + l15;
          int ps = (kc * 4 + l4) ^ (d & 7);
          bf16x8 vf = *(const bf16x8*)&Vb[d * 64 + ps * 8];
          if (act0) acc[0][dt] = __builtin_amdgcn_mfma_f32_16x16x32_bf16(pa0, vf, acc[0][dt], 0, 0, 0);
          acc[1][dt] = __builtin_amdgcn_mfma_f32_16x16x32_bf16(pa1, vf, acc[1][dt], 0, 0, 0);
        }
      }
    }
    __syncthreads();
  }

#pragma unroll
  for (int qt = 0; qt < 2; qt++) {
    float lr[4];
#pragma unroll
    for (int r = 0; r < 4; r++) lr[r] = __shfl(lsum[qt], l4 * 4 + r);
#pragma unroll
    for (int dt = 0; dt < 8; dt++)
#pragma unroll
      for (int r = 0; r < 4; r++) {
        int row = qw + qt * 16 + l4 * 4 + r;
        out[((size_t)(b * Ss) + row) * Hdim + (size_t)h * HDs + dt * 16 + l15] =
            f2bf(acc[qt][dt][r] / lr[r]);
      }
  }
}

// ---------------- launcher ----------------
extern "C" void kernel_launch(void* const* d_in, const int* in_sizes, int n_in,
                              void* d_out, int out_size, void* d_ws, size_t ws_size,
                              hipStream_t stream) {
  const float* hidden = (const float*)d_in[0];
  const int* positions = (const int*)d_in[1];
  const float* wqkv = (const float*)d_in[2];
  const float* wo = (const float*)d_in[3];
  float* out = (float*)d_out;
  char* ws = (char*)d_ws;

  // workspace layout (peak 142.6 MB):
  //   ws0: hidden_bf16 [4096][4096]     (33.5 MB)  -- later reused as attn_out
  //   ws1: weightT bf16 (wqkvT then woT) (50.3 MB)
  //   ws2: qkv bf16 [4096][6144]        (50.3 MB)
  //   ws3: vt bf16 [B*NKV][128][2048]   ( 8.4 MB)
  unsigned short* hbf  = (unsigned short*)(ws);
  unsigned short* wT   = (unsigned short*)(ws + 33554432);
  unsigned short* qkvb = (unsigned short*)(ws + 83886080);
  unsigned short* vtb  = (unsigned short*)(ws + 134217728);

  // 1. hidden fp32 -> bf16
  k_f32_to_bf16<<<16384, 256, 0, stream>>>(hidden, hbf, Bb * Ss * Hdim);
  // 2. wqkv [4096][6144] -> wqkvT bf16 [6144][4096]
  k_transpose_bf16<<<dim3(QKV_N / 32, Hdim / 32), dim3(32, 8), 0, stream>>>(wqkv, wT, Hdim, QKV_N);
  // 3. qkv = hidden @ wqkv   (bf16 out) -- 8-phase GEMM, grid 16*48=768 (%8==0)
  k_gemm8<1><<<(4096 / 256) * (QKV_N / 128), 512, 0, stream>>>(hbf, wT, qkvb, 4096, QKV_N, 4096, QKV_N / 128);
  // 4. RoPE in-place (q scaled by SCALE)
  k_rope<<<dim3(10, Bb * Ss), 256, 0, stream>>>(qkvb, positions);
  // 5. V -> V^T per (b, kv head)
  k_vt<<<dim3(Ss / 32, HDs / 32, Bb * NKV), dim3(32, 8), 0, stream>>>(qkvb, vtb);
  // 6. wo [4096][4096] -> woT bf16 (reuses ws1; ordered after GEMM1 on stream)
  k_transpose_bf16<<<dim3(Hdim / 32, Hdim / 32), dim3(32, 8), 0, stream>>>(wo, wT, Hdim, Hdim);
  // 7. flash attention v2 -> attn_out (reuses ws0)
  k_attn<<<Bb * NH * (Ss / 128), 256, 0, stream>>>(qkvb, vtb, hbf);
  // 8. out = attn_out @ wo  (fp32 out) -- grid 16*32=512 (%8==0)
  k_gemm8<0><<<(4096 / 256) * (4096 / 128), 512, 0, stream>>>(hbf, wT, out, 4096, 4096, 4096, 4096 / 128);
}